// Round 10
// baseline (192.031 us; speedup 1.0000x reference)
//
#include <hip/hip_runtime.h>
#include <hip/hip_bf16.h>

typedef __attribute__((ext_vector_type(8))) unsigned short ushort8;
typedef __attribute__((ext_vector_type(8))) __bf16 bf16x8;
typedef __attribute__((ext_vector_type(4))) float f32x4;
typedef __attribute__((ext_vector_type(4))) float floatx4;

__device__ __forceinline__ unsigned short f2bf(float f) {
    unsigned u = __builtin_bit_cast(unsigned, f);
    u += 0x7fffu + ((u >> 16) & 1u);   // RNE
    return (unsigned short)(u >> 16);
}
__device__ __forceinline__ float bf2f(unsigned short h) {
    unsigned u = ((unsigned)h) << 16;
    return __builtin_bit_cast(float, u);
}

__device__ __forceinline__ void gload_lds16(const void* g, void* l) {
    __builtin_amdgcn_global_load_lds(
        (const __attribute__((address_space(1))) void*)g,
        (__attribute__((address_space(3))) void*)l,
        16, 0, 0);
}

#define BAR()   asm volatile("s_barrier" ::: "memory")
#define VMW3()  asm volatile("s_waitcnt vmcnt(3)" ::: "memory")
#define VMW0()  asm volatile("s_waitcnt vmcnt(0)" ::: "memory")

// ---------------- f32 -> bf16 conversion (8 elems/thread) ----------------
__global__ __launch_bounds__(256) void cvt_f2bf(const float* __restrict__ in,
                                                unsigned short* __restrict__ out,
                                                int n8) {
    int i = blockIdx.x * 256 + threadIdx.x;
    if (i >= n8) return;
    floatx4 a = ((const floatx4*)in)[2 * i];
    floatx4 b = ((const floatx4*)in)[2 * i + 1];
    ushort8 o;
#pragma unroll
    for (int j = 0; j < 4; ++j) { o[j] = f2bf(a[j]); o[4 + j] = f2bf(b[j]); }
    ((ushort8*)out)[i] = o;
}

// ---- Weff[o][j] = g[j]*fcW[o][j] + g[j+2048]*fcW[o][j+2048] (bf16) -------
__global__ __launch_bounds__(256) void weff_kernel(const float* __restrict__ fcW,
                                                   const float* __restrict__ lng,
                                                   const float* __restrict__ lnb,
                                                   const float* __restrict__ fcb,
                                                   unsigned short* __restrict__ weff,
                                                   float* __restrict__ cc,
                                                   float* __restrict__ wsum) {
    int o = blockIdx.x;
    int tid = threadIdx.x;
    if (o >= 1000) {
        ushort8 z = {0, 0, 0, 0, 0, 0, 0, 0};
        ((ushort8*)(weff + (size_t)o * 2048))[tid] = z;
        if (tid == 0) { cc[o] = 0.f; wsum[o] = 0.f; }
        return;
    }
    const float* wrow = fcW + (size_t)o * 4096;
    int j0 = tid * 8;
    floatx4 wa  = *(const floatx4*)(wrow + j0);
    floatx4 wb  = *(const floatx4*)(wrow + j0 + 4);
    floatx4 wa2 = *(const floatx4*)(wrow + 2048 + j0);
    floatx4 wb2 = *(const floatx4*)(wrow + 2048 + j0 + 4);
    floatx4 ga  = *(const floatx4*)(lng + j0);
    floatx4 gb  = *(const floatx4*)(lng + j0 + 4);
    floatx4 ga2 = *(const floatx4*)(lng + 2048 + j0);
    floatx4 gb2 = *(const floatx4*)(lng + 2048 + j0 + 4);
    floatx4 ba  = *(const floatx4*)(lnb + j0);
    floatx4 bb  = *(const floatx4*)(lnb + j0 + 4);
    floatx4 ba2 = *(const floatx4*)(lnb + 2048 + j0);
    floatx4 bb2 = *(const floatx4*)(lnb + 2048 + j0 + 4);
    ushort8 o8;
    float acc = 0.f, ws = 0.f;
#pragma unroll
    for (int j = 0; j < 4; ++j) {
        o8[j] = f2bf(ga[j] * wa[j] + ga2[j] * wa2[j]);
        acc += ba[j] * wa[j] + ba2[j] * wa2[j];
        ws  += bf2f(o8[j]);
        o8[4 + j] = f2bf(gb[j] * wb[j] + gb2[j] * wb2[j]);
        acc += bb[j] * wb[j] + bb2[j] * wb2[j];
        ws  += bf2f(o8[4 + j]);
    }
    ((ushort8*)(weff + (size_t)o * 2048))[tid] = o8;
#pragma unroll
    for (int d = 32; d; d >>= 1) { acc += __shfl_down(acc, d); ws += __shfl_down(ws, d); }
    __shared__ float red[4], redw[4];
    if ((tid & 63) == 0) { red[tid >> 6] = acc; redw[tid >> 6] = ws; }
    __syncthreads();
    if (tid == 0) {
        cc[o] = fcb[o] + red[0] + red[1] + red[2] + red[3];
        wsum[o] = redw[0] + redw[1] + redw[2] + redw[3];
    }
}

// -------- row LN stats: mur[row] = {mu, rsqrt(var+eps)} over h2 row -------
__global__ __launch_bounds__(256) void ln_stats(const unsigned short* __restrict__ h2,
                                                float2* __restrict__ mur) {
    int row = blockIdx.x, tid = threadIdx.x;
    ushort8 v = ((const ushort8*)(h2 + (size_t)row * 2048))[tid];
    float s = 0.f, s2 = 0.f;
#pragma unroll
    for (int j = 0; j < 8; ++j) { float f = bf2f(v[j]); s += f; s2 += f * f; }
#pragma unroll
    for (int d = 32; d; d >>= 1) { s += __shfl_down(s, d); s2 += __shfl_down(s2, d); }
    __shared__ float rs_[4], rs2_[4];
    if ((tid & 63) == 0) { rs_[tid >> 6] = s; rs2_[tid >> 6] = s2; }
    __syncthreads();
    if (tid == 0) {
        float S = rs_[0] + rs_[1] + rs_[2] + rs_[3];
        float S2 = rs2_[0] + rs2_[1] + rs2_[2] + rs2_[3];
        float mu = S * (1.f / 2048.f);
        float var = S2 * (1.f / 2048.f) - mu * mu;
        mur[row] = make_float2(mu, rsqrtf(var + 1e-5f));
    }
}

// ---- reduce: out = bf16(tanh(P0 + P1 + b0[col] + b1[col])), 8/thread ----
__global__ __launch_bounds__(256) void reduce_tanh(const unsigned short* __restrict__ P0,
                                                   const unsigned short* __restrict__ P1,
                                                   const float* __restrict__ b0,
                                                   const float* __restrict__ b1,
                                                   unsigned short* __restrict__ out) {
    int i = blockIdx.x * 256 + threadIdx.x;
    ushort8 p0 = ((const ushort8*)P0)[i];
    ushort8 p1 = ((const ushort8*)P1)[i];
    int c0 = (i * 8) & 2047;
    floatx4 ba = *(const floatx4*)(b0 + c0), bb = *(const floatx4*)(b0 + c0 + 4);
    floatx4 ca = *(const floatx4*)(b1 + c0), cb = *(const floatx4*)(b1 + c0 + 4);
    ushort8 o;
#pragma unroll
    for (int j = 0; j < 4; ++j) {
        o[j]     = f2bf(tanhf(bf2f(p0[j])     + bf2f(p1[j])     + ba[j] + ca[j]));
        o[4 + j] = f2bf(tanhf(bf2f(p0[4 + j]) + bf2f(p1[4 + j]) + bb[j] + cb[j]));
    }
    ((ushort8*)out)[i] = o;
}

// == 2-blocks/CU free-run split-K bf16 GEMM: BM=128, BN=256, BK=32 =========
// 512 threads (8 waves 2M x 4N), per-wave C = 64x64 (acc[4][4]).
// LDS 3 x 24KB = 72KB -> TWO blocks per CU (the untested axis): when one
// block sits at its tile-boundary vmcnt/barrier, the other block's 8 waves
// keep the MFMA+LDS pipes fed (m97's implicit TLP overlap regime).
// Grid 512 blocks via split-K=2 (bf16 partials + reduce_tanh, validated).
// Chunk swizzle for 64B rows: stored chunk position p = c ^ ((row>>1)&3);
// per 16-lane HW phase each 16B slot of the 128B bank period is hit by
// exactly 2 lanes -> free 2-way (r1's linear BK=32 was 8-way, 8.4M confl).
// Inverse swizzle on gload SOURCE, linear dest (rule 21).
__global__ __launch_bounds__(512, 4) void gemm_fs(const unsigned short* __restrict__ A,
                                                  const unsigned short* __restrict__ B,
                                                  int Ks, int KP, int N,
                                                  unsigned short* __restrict__ Pa,
                                                  unsigned short* __restrict__ Pb) {
    extern __shared__ char smem[];
    constexpr int BUFSZ = 24576;   // A 8KB (128x64B) + B 16KB (256x64B)
    const int tid = threadIdx.x;
    const int lane = tid & 63, wid = tid >> 6;
    const int wm = wid >> 2, wn = wid & 3;      // 2M x 4N wave grid
    const int fr = lane & 15, g = lane >> 4;
    const int kp = blockIdx.z;

    // XCD-aware bijective swizzle (nwg = 256, %8==0)
    const int gx = gridDim.x;
    const int nwg = gx * gridDim.y;
    const int fid = blockIdx.y * gx + blockIdx.x;
    const int cpx = nwg >> 3;
    const int sw = (fid & 7) * cpx + (fid >> 3);
    const int bx = sw % gx, by = sw / gx;
    const int row0 = by * 128, col0 = bx * 256;
    const int kbase = kp * KP;

    // staging: dest byte = tid*16 (linear); row = tid>>2, chunk p = tid&3.
    // source chunk c = p ^ ((row>>1)&3) = (tid&3) ^ ((tid>>3)&3)
    const int srow = tid >> 2;
    const int scolE = ((tid & 3) ^ ((tid >> 3) & 3)) * 8;   // elems
    auto stage = [&](int kt, char* buf) {
        const size_t koff = (size_t)(kbase + kt * 32 + scolE);
        gload_lds16(A + (size_t)(row0 + srow) * Ks + koff, buf + tid * 16);
#pragma unroll
        for (int gg = 0; gg < 2; ++gg)
            gload_lds16(B + (size_t)(col0 + gg * 128 + srow) * Ks + koff,
                        buf + 8192 + gg * 8192 + tid * 16);
    };

    // frag read: row = base16 + fr (base16 mult of 16) -> (row>>1)&3 = (fr>>1)&3
    const int kb = (g ^ ((fr >> 1) & 3)) * 16;   // swizzled chunk byte, const/lane

#define LDF(p) __builtin_bit_cast(bf16x8, *(const ushort8*)(p))

    f32x4 acc[4][4];
#pragma unroll
    for (int i = 0; i < 4; ++i)
#pragma unroll
        for (int j = 0; j < 4; ++j) acc[i][j] = f32x4{0.f, 0.f, 0.f, 0.f};

    char* p0 = smem;
    char* p1 = smem + BUFSZ;
    char* p2 = smem + 2 * BUFSZ;

    // prologue: stage tiles 0,1
    stage(0, p0); stage(1, p1);

    const int NT = KP >> 5;
    for (int t = 0; t < NT; ++t) {
        if (t < NT - 1) { VMW3(); } else { VMW0(); }   // tile t landed
        BAR();   // all waves' stages landed; all done reading buf(t-1)==p2
        if (t + 2 < NT) stage(t + 2, p2);

        bf16x8 aF[4], bF[4];
#pragma unroll
        for (int m = 0; m < 4; ++m)
            aF[m] = LDF(p0 + (wm * 64 + m * 16 + fr) * 64 + kb);
#pragma unroll
        for (int n = 0; n < 4; ++n)
            bF[n] = LDF(p0 + 8192 + (wn * 64 + n * 16 + fr) * 64 + kb);

        __builtin_amdgcn_s_setprio(1);
#pragma unroll
        for (int m = 0; m < 4; ++m)
#pragma unroll
            for (int n = 0; n < 4; ++n)
                acc[m][n] = __builtin_amdgcn_mfma_f32_16x16x32_bf16(aF[m], bF[n], acc[m][n], 0, 0, 0);
        __builtin_amdgcn_s_setprio(0);

        char* tmp = p0; p0 = p1; p1 = p2; p2 = tmp;
    }

    // ---- epilogue: bf16 partial store ----
    unsigned short* P = kp ? Pb : Pa;
#pragma unroll
    for (int m = 0; m < 4; ++m) {
        int rbase = row0 + wm * 64 + m * 16 + g * 4;
#pragma unroll
        for (int n = 0; n < 4; ++n) {
            int col = col0 + wn * 64 + n * 16 + fr;
#pragma unroll
            for (int r = 0; r < 4; ++r)
                P[(size_t)(rbase + r) * N + col] = f2bf(acc[m][n][r]);
        }
    }
#undef LDF
}

// == reg-pipelined bf16 GEMM (round-6 structure) for the classifier GEMM ==
template <int EPI, int NJ>
__global__ __launch_bounds__(512, 2) void gemm_rp(const unsigned short* __restrict__ A,
                                                  const unsigned short* __restrict__ B,
                                                  int M, int N, int K,
                                                  const float* __restrict__ bias0,
                                                  const float* __restrict__ bias1,
                                                  void* __restrict__ Cout, int ncols,
                                                  const float2* __restrict__ mur,
                                                  const float* __restrict__ wsum) {
    extern __shared__ char smem[];
    constexpr int BUFSZ = 16384 + NJ * 8192;
    const int tid = threadIdx.x;
    const int lane = tid & 63, wid = tid >> 6;
    const int wm = wid >> 2, wn = wid & 3;
    const int fr = lane & 15, g = lane >> 4;

    const int nwg = gridDim.x * gridDim.y;
    const int fid = blockIdx.y * gridDim.x + blockIdx.x;
    const int cpx = nwg >> 3;
    const int sw = (fid & 7) * cpx + (fid >> 3);
    const int bx = sw % gridDim.x, by = sw / gridDim.x;
    const int row0 = by * 128, col0 = bx * (64 * NJ);

    const int tg = tid >> 3;
    const int tcE = ((tid & 7) ^ (tg & 7)) * 8;

    auto stage = [&](int kt, char* buf) {
#pragma unroll
        for (int r = 0; r < 2; ++r)
            gload_lds16(A + (size_t)(row0 + r * 64 + tg) * K + kt * 64 + tcE,
                        buf + r * 8192 + wid * 1024);
#pragma unroll
        for (int rr = 0; rr < NJ; ++rr)
            gload_lds16(B + (size_t)(col0 + rr * 64 + tg) * K + kt * 64 + tcE,
                        buf + 16384 + rr * 8192 + wid * 1024);
    };

    const int xorv = (fr & 7) << 4;
    auto readFrags = [&](bf16x8 (&fa)[4][2], bf16x8 (&fb)[NJ][2], const char* buf) {
#pragma unroll
        for (int m = 0; m < 4; ++m)
#pragma unroll
            for (int kh = 0; kh < 2; ++kh)
                fa[m][kh] = __builtin_bit_cast(bf16x8, *(const ushort8*)(
                    buf + (wm * 64 + m * 16 + fr) * 128 + ((kh * 64 + g * 16) ^ xorv)));
#pragma unroll
        for (int n = 0; n < NJ; ++n)
#pragma unroll
            for (int kh = 0; kh < 2; ++kh)
                fb[n][kh] = __builtin_bit_cast(bf16x8, *(const ushort8*)(
                    buf + 16384 + (wn * (16 * NJ) + n * 16 + fr) * 128 + ((kh * 64 + g * 16) ^ xorv)));
    };

    f32x4 acc[4][NJ];
#pragma unroll
    for (int i = 0; i < 4; ++i)
#pragma unroll
        for (int j = 0; j < NJ; ++j) acc[i][j] = f32x4{0.f, 0.f, 0.f, 0.f};

    auto domfma = [&](bf16x8 (&fa)[4][2], bf16x8 (&fb)[NJ][2]) {
        __builtin_amdgcn_s_setprio(1);
#pragma unroll
        for (int m = 0; m < 4; ++m)
#pragma unroll
            for (int n = 0; n < NJ; ++n)
#pragma unroll
                for (int kh = 0; kh < 2; ++kh)
                    acc[m][n] = __builtin_amdgcn_mfma_f32_16x16x32_bf16(fa[m][kh], fb[n][kh], acc[m][n], 0, 0, 0);
        __builtin_amdgcn_s_setprio(0);
    };

    bf16x8 aX[4][2], bX[NJ][2], aY[4][2], bY[NJ][2];

    stage(0, smem); stage(1, smem + BUFSZ);
    if constexpr (NJ == 4) { asm volatile("s_waitcnt vmcnt(6)" ::: "memory"); }
    else                   { asm volatile("s_waitcnt vmcnt(4)" ::: "memory"); }
    BAR();
    readFrags(aX, bX, smem);

    const int NT = K >> 6;
    for (int t = 0; t < NT; t += 2) {
        if (t + 2 < NT) {
            stage(t + 2, smem + ((t + 2) % 3) * BUFSZ);
            if constexpr (NJ == 4) { asm volatile("s_waitcnt vmcnt(6)" ::: "memory"); }
            else                   { asm volatile("s_waitcnt vmcnt(4)" ::: "memory"); }
        } else {
            VMW0();
        }
        BAR();
        readFrags(aY, bY, smem + ((t + 1) % 3) * BUFSZ);
        domfma(aX, bX);

        if (t + 2 < NT) {
            if (t + 3 < NT) {
                stage(t + 3, smem + ((t + 3) % 3) * BUFSZ);
                if constexpr (NJ == 4) { asm volatile("s_waitcnt vmcnt(6)" ::: "memory"); }
                else                   { asm volatile("s_waitcnt vmcnt(4)" ::: "memory"); }
            } else {
                VMW0();
            }
            BAR();
            readFrags(aX, bX, smem + ((t + 2) % 3) * BUFSZ);
        }
        domfma(aY, bY);
    }

#pragma unroll
    for (int i = 0; i < 4; ++i) {
        int rbase = row0 + wm * 64 + i * 16 + g * 4;
        if (EPI == 0) {
#pragma unroll
            for (int j = 0; j < NJ; ++j) {
                int col = col0 + wn * (16 * NJ) + j * 16 + fr;
                float bsum = bias0[col] + bias1[col];
                unsigned short* O = (unsigned short*)Cout;
#pragma unroll
                for (int r = 0; r < 4; ++r)
                    O[(size_t)(rbase + r) * N + col] = f2bf(tanhf(acc[i][j][r] + bsum));
            }
        } else {
            float2 mr[4];
#pragma unroll
            for (int r = 0; r < 4; ++r) mr[r] = mur[rbase + r];
#pragma unroll
            for (int j = 0; j < NJ; ++j) {
                int col = col0 + wn * (16 * NJ) + j * 16 + fr;
                if (col < ncols) {
                    float ws = wsum[col];
                    float ccv = bias0[col];
                    float* O = (float*)Cout;
#pragma unroll
                    for (int r = 0; r < 4; ++r)
                        O[(size_t)(rbase + r) * ncols + col] =
                            mr[r].y * (acc[i][j][r] - mr[r].x * ws) + ccv;
                }
            }
        }
    }
}

extern "C" void kernel_launch(void* const* d_in, const int* in_sizes, int n_in,
                              void* d_out, int out_size, void* d_ws, size_t ws_size,
                              hipStream_t stream) {
    const float* x   = (const float*)d_in[0];
    const float* W0  = (const float*)d_in[1];
    const float* bi0 = (const float*)d_in[2];
    const float* bh0 = (const float*)d_in[3];
    const float* W1  = (const float*)d_in[4];
    const float* bi1 = (const float*)d_in[5];
    const float* bh1 = (const float*)d_in[6];
    const float* lng = (const float*)d_in[7];
    const float* lnb = (const float*)d_in[8];
    const float* fcW = (const float*)d_in[9];
    const float* fcb = (const float*)d_in[10];
    float* out = (float*)d_out;

    char* w = (char*)d_ws;
    unsigned short* xb   = (unsigned short*)(w);                  // 4096x4096 bf16
    unsigned short* w0b  = (unsigned short*)(w + 33554432ull);    // 2048x4096 bf16
    unsigned short* w1b  = (unsigned short*)(w + 50331648ull);    // 2048x2048 bf16
    unsigned short* h1   = (unsigned short*)(w + 58720256ull);    // 4096x2048 bf16
    unsigned short* h2   = (unsigned short*)(w + 75497472ull);    // 4096x2048 bf16
    unsigned short* weff = (unsigned short*)(w + 92274688ull);    // 1024x2048 bf16
    float* cc            = (float*)(w + 96468992ull);             // 1024 f32
    float* wsum          = (float*)(w + 96473088ull);             // 1024 f32
    float2* mur          = (float2*)(w + 96477184ull);            // 4096 float2
    // gemm1 partials: P0 aliases the (not-yet-written) h2 region; P1 is fresh
    unsigned short* P1a  = h2;                                    // 16MB
    unsigned short* P1b  = (unsigned short*)(w + 96509952ull);    // 16MB
    // gemm2 partials alias xb (dead after gemm1)
    unsigned short* P2a  = xb;
    unsigned short* P2b  = (unsigned short*)(w + 16777216ull);

    const int SHMF = 73728;                    // 3 x 24KB -> 2 blocks/CU
    const int SHM1 = 3 * (16384 + 2 * 8192);   // 98304
    (void)hipFuncSetAttribute((const void*)gemm_fs,
                              hipFuncAttributeMaxDynamicSharedMemorySize, SHMF);
    (void)hipFuncSetAttribute((const void*)gemm_rp<1, 2>,
                              hipFuncAttributeMaxDynamicSharedMemorySize, SHM1);

    cvt_f2bf<<<8192, 256, 0, stream>>>(x,  xb,  2097152);
    cvt_f2bf<<<4096, 256, 0, stream>>>(W0, w0b, 1048576);
    cvt_f2bf<<<2048, 256, 0, stream>>>(W1, w1b, 524288);
    weff_kernel<<<1024, 256, 0, stream>>>(fcW, lng, lnb, fcb, weff, cc, wsum);

    // gemm1: x @ W0^T, split-K=2 (KP=2048), 512 blocks = 2/CU, bf16 partials
    gemm_fs<<<dim3(8, 32, 2), 512, SHMF, stream>>>(xb, w0b, 4096, 2048, 2048, P1a, P1b);
    // h1 = tanh(P0 + P1 + b_ih0 + b_hh0)
    reduce_tanh<<<4096, 256, 0, stream>>>(P1a, P1b, bi0, bh0, h1);

    // gemm2: h1 @ W1^T, split-K=2 (KP=1024)
    gemm_fs<<<dim3(8, 32, 2), 512, SHMF, stream>>>(h1, w1b, 2048, 1024, 2048, P2a, P2b);
    // h2 = tanh(P0 + P1 + b_ih1 + b_hh1)
    reduce_tanh<<<4096, 256, 0, stream>>>(P2a, P2b, bi1, bh1, h2);

    // per-row LN stats of h2
    ln_stats<<<4096, 256, 0, stream>>>(h2, mur);
    // out = r*(h2 @ Weff^T - mu*wsum) + cc   (LN folded into epilogue)
    gemm_rp<1, 2><<<dim3(8, 32), 512, SHM1, stream>>>(h2, weff, 4096, 1024, 2048,
                                                      cc, nullptr, out, 1000, mur, wsum);
}

// Round 11
// 170.323 us; speedup vs baseline: 1.1275x; 1.1275x over previous
//
#include <hip/hip_runtime.h>
#include <hip/hip_bf16.h>

typedef __attribute__((ext_vector_type(8))) unsigned short ushort8;
typedef __attribute__((ext_vector_type(8))) __bf16 bf16x8;
typedef __attribute__((ext_vector_type(4))) float f32x4;
typedef __attribute__((ext_vector_type(4))) float floatx4;

__device__ __forceinline__ unsigned short f2bf(float f) {
    unsigned u = __builtin_bit_cast(unsigned, f);
    u += 0x7fffu + ((u >> 16) & 1u);   // RNE
    return (unsigned short)(u >> 16);
}
__device__ __forceinline__ float bf2f(unsigned short h) {
    unsigned u = ((unsigned)h) << 16;
    return __builtin_bit_cast(float, u);
}

__device__ __forceinline__ void gload_lds16(const void* g, void* l) {
    __builtin_amdgcn_global_load_lds(
        (const __attribute__((address_space(1))) void*)g,
        (__attribute__((address_space(3))) void*)l,
        16, 0, 0);
}

#define BAR()   asm volatile("s_barrier" ::: "memory")
#define VMW0()  asm volatile("s_waitcnt vmcnt(0)" ::: "memory")

// ===== merged prep: 3 f32->bf16 converts + Weff, one dispatch ============
// blocks [0,8192)      : cvt x      (2097152 x 8 elems)
// blocks [8192,12288)  : cvt W0     (1048576 x 8)
// blocks [12288,14336) : cvt W1     (524288 x 8)
// blocks [14336,15360) : weff row o = b - 14336
__global__ __launch_bounds__(256) void prep_kernel(
        const float* __restrict__ x,   unsigned short* __restrict__ xb,
        const float* __restrict__ W0,  unsigned short* __restrict__ w0b,
        const float* __restrict__ W1,  unsigned short* __restrict__ w1b,
        const float* __restrict__ fcW, const float* __restrict__ lng,
        const float* __restrict__ lnb, const float* __restrict__ fcb,
        unsigned short* __restrict__ weff, float* __restrict__ cc,
        float* __restrict__ wsum) {
    const int b = blockIdx.x;
    const int tid = threadIdx.x;
    __shared__ float red[4], redw[4];

    if (b < 14336) {
        const float* in; unsigned short* out; int i;
        if (b < 8192)       { in = x;  out = xb;  i = b * 256 + tid; }
        else if (b < 12288) { in = W0; out = w0b; i = (b - 8192) * 256 + tid; }
        else                { in = W1; out = w1b; i = (b - 12288) * 256 + tid; }
        floatx4 a = ((const floatx4*)in)[2 * i];
        floatx4 c = ((const floatx4*)in)[2 * i + 1];
        ushort8 o;
#pragma unroll
        for (int j = 0; j < 4; ++j) { o[j] = f2bf(a[j]); o[4 + j] = f2bf(c[j]); }
        ((ushort8*)out)[i] = o;
        return;
    }

    const int o = b - 14336;
    if (o >= 1000) {
        ushort8 z = {0, 0, 0, 0, 0, 0, 0, 0};
        ((ushort8*)(weff + (size_t)o * 2048))[tid] = z;
        if (tid == 0) { cc[o] = 0.f; wsum[o] = 0.f; }
        return;
    }
    const float* wrow = fcW + (size_t)o * 4096;
    int j0 = tid * 8;
    floatx4 wa  = *(const floatx4*)(wrow + j0);
    floatx4 wb  = *(const floatx4*)(wrow + j0 + 4);
    floatx4 wa2 = *(const floatx4*)(wrow + 2048 + j0);
    floatx4 wb2 = *(const floatx4*)(wrow + 2048 + j0 + 4);
    floatx4 ga  = *(const floatx4*)(lng + j0);
    floatx4 gb  = *(const floatx4*)(lng + j0 + 4);
    floatx4 ga2 = *(const floatx4*)(lng + 2048 + j0);
    floatx4 gb2 = *(const floatx4*)(lng + 2048 + j0 + 4);
    floatx4 ba  = *(const floatx4*)(lnb + j0);
    floatx4 bb  = *(const floatx4*)(lnb + j0 + 4);
    floatx4 ba2 = *(const floatx4*)(lnb + 2048 + j0);
    floatx4 bb2 = *(const floatx4*)(lnb + 2048 + j0 + 4);
    ushort8 o8;
    float acc = 0.f, ws = 0.f;
#pragma unroll
    for (int j = 0; j < 4; ++j) {
        o8[j] = f2bf(ga[j] * wa[j] + ga2[j] * wa2[j]);
        acc += ba[j] * wa[j] + ba2[j] * wa2[j];
        ws  += bf2f(o8[j]);
        o8[4 + j] = f2bf(gb[j] * wb[j] + gb2[j] * wb2[j]);
        acc += bb[j] * wb[j] + bb2[j] * wb2[j];
        ws  += bf2f(o8[4 + j]);
    }
    ((ushort8*)(weff + (size_t)o * 2048))[tid] = o8;
#pragma unroll
    for (int d = 32; d; d >>= 1) { acc += __shfl_down(acc, d); ws += __shfl_down(ws, d); }
    if ((tid & 63) == 0) { red[tid >> 6] = acc; redw[tid >> 6] = ws; }
    __syncthreads();
    if (tid == 0) {
        cc[o] = fcb[o] + red[0] + red[1] + red[2] + red[3];
        wsum[o] = redw[0] + redw[1] + redw[2] + redw[3];
    }
}

// -------- row LN stats: mur[row] = {mu, rsqrt(var+eps)} over h2 row -------
__global__ __launch_bounds__(256) void ln_stats(const unsigned short* __restrict__ h2,
                                                float2* __restrict__ mur) {
    int row = blockIdx.x, tid = threadIdx.x;
    ushort8 v = ((const ushort8*)(h2 + (size_t)row * 2048))[tid];
    float s = 0.f, s2 = 0.f;
#pragma unroll
    for (int j = 0; j < 8; ++j) { float f = bf2f(v[j]); s += f; s2 += f * f; }
#pragma unroll
    for (int d = 32; d; d >>= 1) { s += __shfl_down(s, d); s2 += __shfl_down(s2, d); }
    __shared__ float rs_[4], rs2_[4];
    if ((tid & 63) == 0) { rs_[tid >> 6] = s; rs2_[tid >> 6] = s2; }
    __syncthreads();
    if (tid == 0) {
        float S = rs_[0] + rs_[1] + rs_[2] + rs_[3];
        float S2 = rs2_[0] + rs2_[1] + rs2_[2] + rs2_[3];
        float mu = S * (1.f / 2048.f);
        float var = S2 * (1.f / 2048.f) - mu * mu;
        mur[row] = make_float2(mu, rsqrtf(var + 1e-5f));
    }
}

// == reg-pipelined bf16 GEMM: C[M,N] = A[M,K]*B[N,K]^T, BK=64, 3 LDS bufs ==
// BM=128, BN=64*NJ, 512 threads (8 waves 2M x 4N), per-wave C = 64 x 16*NJ.
// Cross-tile register double-buffer; counted vmcnt keeps one tile's stage
// loads in flight across the barrier. 128B rows, byte ^= (row&7)<<4 swizzle
// (0 conflicts measured). Best-known structure (r6: gemm1 78us / 880 TF).
// EPI 0: bf16 out = tanh(acc + bias0[n] + bias1[n]), stride N
// EPI 1: f32 out = mur[row].y*(acc - mur[row].x*wsum[col]) + bias0[col]
template <int EPI, int NJ>
__global__ __launch_bounds__(512, 2) void gemm_rp(const unsigned short* __restrict__ A,
                                                  const unsigned short* __restrict__ B,
                                                  int M, int N, int K,
                                                  const float* __restrict__ bias0,
                                                  const float* __restrict__ bias1,
                                                  void* __restrict__ Cout, int ncols,
                                                  const float2* __restrict__ mur,
                                                  const float* __restrict__ wsum) {
    extern __shared__ char smem[];
    constexpr int BUFSZ = 16384 + NJ * 8192;   // A (16KB) + B (NJ*8KB), BK=64
    const int tid = threadIdx.x;
    const int lane = tid & 63, wid = tid >> 6;
    const int wm = wid >> 2, wn = wid & 3;      // 2 x 4 wave grid
    const int fr = lane & 15, g = lane >> 4;

    // XCD-aware bijective swizzle (nwg % 8 == 0 for all our launches)
    const int nwg = gridDim.x * gridDim.y;
    const int fid = blockIdx.y * gridDim.x + blockIdx.x;
    const int cpx = nwg >> 3;
    const int sw = (fid & 7) * cpx + (fid >> 3);
    const int bx = sw % gridDim.x, by = sw / gridDim.x;
    const int row0 = by * 128, col0 = bx * (64 * NJ);

    const int tg = tid >> 3;
    const int tcE = ((tid & 7) ^ (tg & 7)) * 8;

    auto stage = [&](int kt, char* buf) {
#pragma unroll
        for (int r = 0; r < 2; ++r)
            gload_lds16(A + (size_t)(row0 + r * 64 + tg) * K + kt * 64 + tcE,
                        buf + r * 8192 + wid * 1024);
#pragma unroll
        for (int rr = 0; rr < NJ; ++rr)
            gload_lds16(B + (size_t)(col0 + rr * 64 + tg) * K + kt * 64 + tcE,
                        buf + 16384 + rr * 8192 + wid * 1024);
    };

    const int xorv = (fr & 7) << 4;
    auto readFrags = [&](bf16x8 (&fa)[4][2], bf16x8 (&fb)[NJ][2], const char* buf) {
#pragma unroll
        for (int m = 0; m < 4; ++m)
#pragma unroll
            for (int kh = 0; kh < 2; ++kh)
                fa[m][kh] = __builtin_bit_cast(bf16x8, *(const ushort8*)(
                    buf + (wm * 64 + m * 16 + fr) * 128 + ((kh * 64 + g * 16) ^ xorv)));
#pragma unroll
        for (int n = 0; n < NJ; ++n)
#pragma unroll
            for (int kh = 0; kh < 2; ++kh)
                fb[n][kh] = __builtin_bit_cast(bf16x8, *(const ushort8*)(
                    buf + 16384 + (wn * (16 * NJ) + n * 16 + fr) * 128 + ((kh * 64 + g * 16) ^ xorv)));
    };

    f32x4 acc[4][NJ];
#pragma unroll
    for (int i = 0; i < 4; ++i)
#pragma unroll
        for (int j = 0; j < NJ; ++j) acc[i][j] = f32x4{0.f, 0.f, 0.f, 0.f};

    auto domfma = [&](bf16x8 (&fa)[4][2], bf16x8 (&fb)[NJ][2]) {
        __builtin_amdgcn_s_setprio(1);
#pragma unroll
        for (int m = 0; m < 4; ++m)
#pragma unroll
            for (int n = 0; n < NJ; ++n)
#pragma unroll
                for (int kh = 0; kh < 2; ++kh)
                    acc[m][n] = __builtin_amdgcn_mfma_f32_16x16x32_bf16(fa[m][kh], fb[n][kh], acc[m][n], 0, 0, 0);
        __builtin_amdgcn_s_setprio(0);
    };

    bf16x8 aX[4][2], bX[NJ][2], aY[4][2], bY[NJ][2];

    stage(0, smem); stage(1, smem + BUFSZ);
    if constexpr (NJ == 4) { asm volatile("s_waitcnt vmcnt(6)" ::: "memory"); }
    else                   { asm volatile("s_waitcnt vmcnt(4)" ::: "memory"); }
    BAR();
    readFrags(aX, bX, smem);

    const int NT = K >> 6;   // always even here
    for (int t = 0; t < NT; t += 2) {
        if (t + 2 < NT) {
            stage(t + 2, smem + ((t + 2) % 3) * BUFSZ);
            if constexpr (NJ == 4) { asm volatile("s_waitcnt vmcnt(6)" ::: "memory"); }
            else                   { asm volatile("s_waitcnt vmcnt(4)" ::: "memory"); }
        } else {
            VMW0();
        }
        BAR();
        readFrags(aY, bY, smem + ((t + 1) % 3) * BUFSZ);
        domfma(aX, bX);

        if (t + 2 < NT) {
            if (t + 3 < NT) {
                stage(t + 3, smem + ((t + 3) % 3) * BUFSZ);
                if constexpr (NJ == 4) { asm volatile("s_waitcnt vmcnt(6)" ::: "memory"); }
                else                   { asm volatile("s_waitcnt vmcnt(4)" ::: "memory"); }
            } else {
                VMW0();
            }
            BAR();
            readFrags(aX, bX, smem + ((t + 2) % 3) * BUFSZ);
        }
        domfma(aY, bY);
    }

    // ---- epilogue ----
#pragma unroll
    for (int i = 0; i < 4; ++i) {
        int rbase = row0 + wm * 64 + i * 16 + g * 4;
        if (EPI == 0) {
#pragma unroll
            for (int j = 0; j < NJ; ++j) {
                int col = col0 + wn * (16 * NJ) + j * 16 + fr;
                float bsum = bias0[col] + bias1[col];
                unsigned short* O = (unsigned short*)Cout;
#pragma unroll
                for (int r = 0; r < 4; ++r)
                    O[(size_t)(rbase + r) * N + col] = f2bf(tanhf(acc[i][j][r] + bsum));
            }
        } else {
            float2 mr[4];
#pragma unroll
            for (int r = 0; r < 4; ++r) mr[r] = mur[rbase + r];
#pragma unroll
            for (int j = 0; j < NJ; ++j) {
                int col = col0 + wn * (16 * NJ) + j * 16 + fr;
                if (col < ncols) {
                    float ws = wsum[col];
                    float ccv = bias0[col];
                    float* O = (float*)Cout;
#pragma unroll
                    for (int r = 0; r < 4; ++r)
                        O[(size_t)(rbase + r) * ncols + col] =
                            mr[r].y * (acc[i][j][r] - mr[r].x * ws) + ccv;
                }
            }
        }
    }
}

extern "C" void kernel_launch(void* const* d_in, const int* in_sizes, int n_in,
                              void* d_out, int out_size, void* d_ws, size_t ws_size,
                              hipStream_t stream) {
    const float* x   = (const float*)d_in[0];
    const float* W0  = (const float*)d_in[1];
    const float* bi0 = (const float*)d_in[2];
    const float* bh0 = (const float*)d_in[3];
    const float* W1  = (const float*)d_in[4];
    const float* bi1 = (const float*)d_in[5];
    const float* bh1 = (const float*)d_in[6];
    const float* lng = (const float*)d_in[7];
    const float* lnb = (const float*)d_in[8];
    const float* fcW = (const float*)d_in[9];
    const float* fcb = (const float*)d_in[10];
    float* out = (float*)d_out;

    char* w = (char*)d_ws;
    unsigned short* xb   = (unsigned short*)(w);                  // 4096x4096 bf16
    unsigned short* w0b  = (unsigned short*)(w + 33554432ull);    // 2048x4096 bf16
    unsigned short* w1b  = (unsigned short*)(w + 50331648ull);    // 2048x2048 bf16
    unsigned short* h1   = (unsigned short*)(w + 58720256ull);    // 4096x2048 bf16
    unsigned short* h2   = (unsigned short*)(w + 75497472ull);    // 4096x2048 bf16
    unsigned short* weff = (unsigned short*)(w + 92274688ull);    // 1024x2048 bf16
    float* cc            = (float*)(w + 96468992ull);             // 1024 f32
    float* wsum          = (float*)(w + 96473088ull);             // 1024 f32
    float2* mur          = (float2*)(w + 96477184ull);            // 4096 float2

    const int SHM0 = 3 * (16384 + 4 * 8192);  // 147456
    const int SHM1 = 3 * (16384 + 2 * 8192);  // 98304
    (void)hipFuncSetAttribute((const void*)gemm_rp<0, 4>,
                              hipFuncAttributeMaxDynamicSharedMemorySize, SHM0);
    (void)hipFuncSetAttribute((const void*)gemm_rp<1, 2>,
                              hipFuncAttributeMaxDynamicSharedMemorySize, SHM1);

    // prep: cvt x/W0/W1 -> bf16 and build Weff/cc/wsum, single dispatch
    prep_kernel<<<15360, 256, 0, stream>>>(x, xb, W0, w0b, W1, w1b,
                                           fcW, lng, lnb, fcb, weff, cc, wsum);
    // h1 = tanh(x @ W0^T + b_ih0 + b_hh0)
    gemm_rp<0, 4><<<dim3(8, 32), 512, SHM0, stream>>>(xb, w0b, 4096, 2048, 4096,
                                                      bi0, bh0, h1, 2048, nullptr, nullptr);
    // h2 = tanh(h1 @ W1^T + b_ih1 + b_hh1)
    gemm_rp<0, 4><<<dim3(8, 32), 512, SHM0, stream>>>(h1, w1b, 4096, 2048, 2048,
                                                      bi1, bh1, h2, 2048, nullptr, nullptr);
    // per-row LN stats of h2 (concat duplicates -> stats over h2 row)
    ln_stats<<<4096, 256, 0, stream>>>(h2, mur);
    // out = r*(h2 @ Weff^T - mu*wsum) + cc   (LN folded into epilogue)
    gemm_rp<1, 2><<<dim3(8, 32), 512, SHM1, stream>>>(h2, weff, 4096, 1024, 2048,
                                                      cc, nullptr, out, 1000, mur, wsum);
}